// Round 2
// baseline (19423.195 us; speedup 1.0000x reference)
//
#include <hip/hip_runtime.h>
#include <hip/hip_bf16.h>
#include <math.h>

#define NN 100000
#define NE 3200000
#define FIN 128
#define HD 64
#define NL 64
#define NC 47

// ---------------- runtime dtype detection ----------------
// flags[0]: 1 = float inputs are fp32, 0 = bf16
// flags[1]: 1 = edge_index is int64, 0 = int32

__global__ void detect_kernel(const void* __restrict__ x, const void* __restrict__ eidx,
                              int* __restrict__ flags) {
    if (threadIdx.x == 0 && blockIdx.x == 0) {
        const unsigned short* u = (const unsigned short*)x;
        int sane = 0;
        for (int i = 0; i < 64; i++) {
            unsigned short v = u[2 * i];          // even half-words: garbage iff fp32 data
            int e = (v >> 7) & 0xFF;
            if ((v & 0x7FFF) == 0 || (e >= 90 && e <= 141)) sane++;
        }
        flags[0] = (sane >= 48) ? 0 : 1;
        const int* e32 = (const int*)eidx;
        int nz = 0;
        for (int i = 0; i < 64; i++) if (e32[2 * i + 1] != 0) nz++;
        flags[1] = (nz == 0) ? 1 : 0;             // all-zero odd words => int64 high halves
    }
}

__device__ __forceinline__ float fin_at(const void* p, int isf32, size_t i) {
    return isf32 ? ((const float*)p)[i]
                 : __bfloat162float(((const __hip_bfloat16*)p)[i]);
}

__device__ __forceinline__ int edge_at(const void* p, int is64, size_t i) {
    return is64 ? (int)((const long long*)p)[i] : ((const int*)p)[i];
}

// ---------------- CSR build ----------------

__global__ void count_kernel(const void* __restrict__ eidx, const int* __restrict__ flags,
                             int* __restrict__ cnt) {
    int e = blockIdx.x * blockDim.x + threadIdx.x;
    if (e < NE) {
        int d = edge_at(eidx, flags[1], (size_t)NE + e);  // edge_index[1] = destinations
        atomicAdd(&cnt[d], 1);
    }
}

__global__ void dinv_kernel(const int* __restrict__ cnt, float* __restrict__ dinv) {
    int i = blockIdx.x * blockDim.x + threadIdx.x;
    if (i < NN) dinv[i] = rsqrtf(1.0f + (float)cnt[i]);  // +1 for self-loop
}

// single-block 1024-thread chunked Hillis-Steele exclusive scan over N counts
__global__ void scan_kernel(const int* __restrict__ cnt, int* __restrict__ row_ptr) {
    __shared__ int lds[1024];
    __shared__ int base_s;
    int tid = threadIdx.x;
    if (tid == 0) base_s = 0;
    __syncthreads();
    for (int chunk = 0; chunk < NN; chunk += 1024) {
        int i = chunk + tid;
        int v = (i < NN) ? cnt[i] : 0;
        lds[tid] = v;
        __syncthreads();
        for (int off = 1; off < 1024; off <<= 1) {
            int t = (tid >= off) ? lds[tid - off] : 0;
            __syncthreads();
            lds[tid] += t;
            __syncthreads();
        }
        int incl = lds[tid];
        int base = base_s;
        if (i < NN) row_ptr[i] = base + incl - v;   // exclusive
        __syncthreads();
        if (tid == 1023) base_s = base + incl;      // incl@1023 == chunk total
        __syncthreads();
    }
    if (tid == 0) row_ptr[NN] = base_s;
}

__global__ void scatter_kernel(const void* __restrict__ eidx, const int* __restrict__ flags,
                               const int* __restrict__ row_ptr, int* __restrict__ fill,
                               const float* __restrict__ dinv,
                               int* __restrict__ col, float* __restrict__ val) {
    int e = blockIdx.x * blockDim.x + threadIdx.x;
    if (e < NE) {
        int is64 = flags[1];
        int s = edge_at(eidx, is64, (size_t)e);           // edge_index[0] = sources
        int d = edge_at(eidx, is64, (size_t)NE + e);      // edge_index[1] = destinations
        int pos = row_ptr[d] + atomicAdd(&fill[d], 1);
        col[pos] = s;
        val[pos] = dinv[d] * dinv[s];
    }
}

// ---------------- x0 = relu(x @ W1 + b1) ----------------

__global__ __launch_bounds__(256) void x0_kernel(const void* __restrict__ x,
                                                 const void* __restrict__ W1,
                                                 const void* __restrict__ b1,
                                                 const int* __restrict__ flags,
                                                 float* __restrict__ x0, float* __restrict__ h) {
    __shared__ float lw[FIN * HD];  // 32 KiB
    int isf = flags[0];
    int tid = threadIdx.x;
    for (int i = tid; i < FIN * HD; i += 256) lw[i] = fin_at(W1, isf, i);
    __syncthreads();
    int row = blockIdx.x * 4 + (tid >> 6);
    int lane = tid & 63;
    if (row >= NN) return;
    float xa = fin_at(x, isf, (size_t)row * FIN + lane);
    float xb = fin_at(x, isf, (size_t)row * FIN + 64 + lane);
    float acc = fin_at(b1, isf, lane);
    #pragma unroll 8
    for (int k = 0; k < 64; k++) {
        float xv = __shfl(xa, k, 64);
        acc += xv * lw[k * HD + lane];
    }
    #pragma unroll 8
    for (int k = 0; k < 64; k++) {
        float xv = __shfl(xb, k, 64);
        acc += xv * lw[(64 + k) * HD + lane];
    }
    float r = fmaxf(acc, 0.0f);
    x0[(size_t)row * HD + lane] = r;
    h[(size_t)row * HD + lane] = r;
}

// ---------------- s = 0.9 * (A_hat @ h) + 0.1 * x0 ----------------

__global__ __launch_bounds__(256) void spmm_kernel(const int* __restrict__ row_ptr,
                                                   const int* __restrict__ col,
                                                   const float* __restrict__ val,
                                                   const float* __restrict__ dinv,
                                                   const float* __restrict__ h,
                                                   const float* __restrict__ x0,
                                                   float* __restrict__ s) {
    int tid = threadIdx.x;
    int row = blockIdx.x * 4 + (tid >> 6);
    int lane = tid & 63;
    if (row >= NN) return;
    float di = dinv[row];
    float acc = di * di * h[(size_t)row * HD + lane];  // self-loop
    int start = row_ptr[row], end = row_ptr[row + 1];
    for (int base = start; base < end; base += 64) {
        int idx = base + lane;
        int cc = 0; float vv = 0.0f;
        if (idx < end) { cc = col[idx]; vv = val[idx]; }
        int n = min(64, end - base);
        for (int j = 0; j < n; j++) {
            int c = __shfl(cc, j, 64);
            float w = __shfl(vv, j, 64);
            acc += w * h[(size_t)c * HD + lane];
        }
    }
    s[(size_t)row * HD + lane] = 0.9f * acc + 0.1f * x0[(size_t)row * HD + lane];
}

// ---------------- h = relu((1-beta)*s + beta*(s @ Wl)) ----------------
// convW element size depends on runtime dtype -> pass layer index, offset on device

__global__ __launch_bounds__(256) void layer_mm(const void* __restrict__ convW, int layer,
                                                const int* __restrict__ flags,
                                                const float* __restrict__ s,
                                                float* __restrict__ h, float beta) {
    __shared__ float lw[HD * HD];  // 16 KiB
    int isf = flags[0];
    size_t wbase = (size_t)layer * HD * HD;
    int tid = threadIdx.x;
    for (int i = tid; i < HD * HD; i += 256) lw[i] = fin_at(convW, isf, wbase + i);
    __syncthreads();
    int row = blockIdx.x * 4 + (tid >> 6);
    int lane = tid & 63;
    if (row >= NN) return;
    float sj = s[(size_t)row * HD + lane];
    float acc = 0.0f;
    #pragma unroll 8
    for (int k = 0; k < 64; k++) {
        float sk = __shfl(sj, k, 64);
        acc += sk * lw[k * HD + lane];
    }
    float r = (1.0f - beta) * sj + beta * acc;
    h[(size_t)row * HD + lane] = fmaxf(r, 0.0f);
}

// ---------------- out = log_softmax(h @ W2 + b2) ----------------

__global__ __launch_bounds__(256) void out_kernel(const float* __restrict__ h,
                                                  const void* __restrict__ W2,
                                                  const void* __restrict__ b2,
                                                  const int* __restrict__ flags,
                                                  void* __restrict__ out) {
    __shared__ float lw[HD * 64];  // padded [64][64], cols >= 47 zero
    int isf = flags[0];
    int tid = threadIdx.x;
    for (int i = tid; i < HD * 64; i += 256) {
        int k = i >> 6, j = i & 63;
        lw[i] = (j < NC) ? fin_at(W2, isf, (size_t)k * NC + j) : 0.0f;
    }
    __syncthreads();
    int row = blockIdx.x * 4 + (tid >> 6);
    int lane = tid & 63;
    if (row >= NN) return;
    float hv = h[(size_t)row * HD + lane];
    float acc = (lane < NC) ? fin_at(b2, isf, lane) : 0.0f;
    #pragma unroll 8
    for (int k = 0; k < 64; k++) {
        float hk = __shfl(hv, k, 64);
        acc += hk * lw[k * 64 + lane];
    }
    float mv = (lane < NC) ? acc : -1e30f;
    for (int off = 32; off > 0; off >>= 1) mv = fmaxf(mv, __shfl_xor(mv, off, 64));
    float ex = (lane < NC) ? expf(acc - mv) : 0.0f;
    float se = ex;
    for (int off = 32; off > 0; off >>= 1) se += __shfl_xor(se, off, 64);
    float res = acc - mv - logf(se);
    if (lane < NC) {
        size_t oi = (size_t)row * NC + lane;
        if (isf) ((float*)out)[oi] = res;
        else     ((__hip_bfloat16*)out)[oi] = __float2bfloat16(res);
    }
}

// ---------------- host ----------------

static inline size_t align256(size_t x) { return (x + 255) & ~(size_t)255; }

extern "C" void kernel_launch(void* const* d_in, const int* in_sizes, int n_in,
                              void* d_out, int out_size, void* d_ws, size_t ws_size,
                              hipStream_t stream) {
    const void* x     = d_in[0];
    const void* eidx  = d_in[1];
    const void* W1    = d_in[2];
    const void* b1    = d_in[3];
    const void* convW = d_in[4];
    const void* W2    = d_in[5];
    const void* b2    = d_in[6];

    char* p = (char*)d_ws;
    size_t off = 0;
    auto alloc = [&](size_t bytes) { void* r = p + off; off += align256(bytes); return r; };
    int*   flags   = (int*)alloc(256);
    int*   cnt     = (int*)alloc((size_t)NN * 4);
    int*   fill    = (int*)alloc((size_t)NN * 4);
    int*   row_ptr = (int*)alloc((size_t)(NN + 1) * 4);
    float* dinv    = (float*)alloc((size_t)NN * 4);
    int*   col     = (int*)alloc((size_t)NE * 4);
    float* val     = (float*)alloc((size_t)NE * 4);
    float* x0      = (float*)alloc((size_t)NN * HD * 4);
    float* hbuf    = (float*)alloc((size_t)NN * HD * 4);
    float* sbuf    = (float*)alloc((size_t)NN * HD * 4);

    detect_kernel<<<1, 64, 0, stream>>>(x, eidx, flags);

    hipMemsetAsync(cnt, 0, (size_t)NN * 4, stream);
    hipMemsetAsync(fill, 0, (size_t)NN * 4, stream);
    count_kernel<<<(NE + 255) / 256, 256, 0, stream>>>(eidx, flags, cnt);
    dinv_kernel<<<(NN + 255) / 256, 256, 0, stream>>>(cnt, dinv);
    scan_kernel<<<1, 1024, 0, stream>>>(cnt, row_ptr);
    scatter_kernel<<<(NE + 255) / 256, 256, 0, stream>>>(eidx, flags, row_ptr, fill, dinv, col, val);

    int rb = (NN + 3) / 4;  // 4 rows (waves) per 256-thread block
    x0_kernel<<<rb, 256, 0, stream>>>(x, W1, b1, flags, x0, hbuf);
    for (int l = 0; l < NL; l++) {
        float beta = logf(0.5f / (float)(l + 1) + 1.0f);
        spmm_kernel<<<rb, 256, 0, stream>>>(row_ptr, col, val, dinv, hbuf, x0, sbuf);
        layer_mm<<<rb, 256, 0, stream>>>(convW, l, flags, sbuf, hbuf, beta);
    }
    out_kernel<<<rb, 256, 0, stream>>>(hbuf, W2, b2, flags, (void*)d_out);
}

// Round 3
// 9154.969 us; speedup vs baseline: 2.1216x; 2.1216x over previous
//
#include <hip/hip_runtime.h>
#include <hip/hip_bf16.h>
#include <math.h>

#define NN 100000
#define NE 3200000
#define FIN 128
#define HD 64
#define NL 64
#define NC 47
#define RPW 4               // rows per wave (packed dense)
#define WPB 4               // waves per block
#define RPB (RPW * WPB)     // rows per block = 16

// ---------------- helpers ----------------

__device__ __forceinline__ float bf2f(unsigned short u) {
    union { unsigned int i; float f; } v; v.i = ((unsigned int)u) << 16; return v.f;
}
__device__ __forceinline__ unsigned short f2bf(float f) {
    __hip_bfloat16 h = __float2bfloat16(f);   // RNE
    return *reinterpret_cast<unsigned short*>(&h);
}
__device__ __forceinline__ float fin_at(const void* p, int isf32, size_t i) {
    return isf32 ? ((const float*)p)[i]
                 : __bfloat162float(((const __hip_bfloat16*)p)[i]);
}
__device__ __forceinline__ int edge_at(const void* p, int is64, size_t i) {
    return is64 ? (int)((const long long*)p)[i] : ((const int*)p)[i];
}

// ---------------- runtime dtype detection ----------------
// flags[0]: 1 = float inputs are fp32, 0 = bf16
// flags[1]: 1 = edge_index is int64, 0 = int32

__global__ void detect_kernel(const void* __restrict__ x, const void* __restrict__ eidx,
                              int* __restrict__ flags) {
    if (threadIdx.x == 0 && blockIdx.x == 0) {
        const unsigned short* u = (const unsigned short*)x;
        int sane = 0;
        for (int i = 0; i < 64; i++) {
            unsigned short v = u[2 * i];
            int e = (v >> 7) & 0xFF;
            if ((v & 0x7FFF) == 0 || (e >= 90 && e <= 141)) sane++;
        }
        flags[0] = (sane >= 48) ? 0 : 1;
        const int* e32 = (const int*)eidx;
        int nz = 0;
        for (int i = 0; i < 64; i++) if (e32[2 * i + 1] != 0) nz++;
        flags[1] = (nz == 0) ? 1 : 0;
    }
}

// ---------------- CSR build ----------------

__global__ void count_kernel(const void* __restrict__ eidx, const int* __restrict__ flags,
                             int* __restrict__ cnt) {
    int e = blockIdx.x * blockDim.x + threadIdx.x;
    if (e < NE) {
        int d = edge_at(eidx, flags[1], (size_t)NE + e);
        atomicAdd(&cnt[d], 1);
    }
}

__global__ void dinv_kernel(const int* __restrict__ cnt, float* __restrict__ dinv) {
    int i = blockIdx.x * blockDim.x + threadIdx.x;
    if (i < NN) dinv[i] = rsqrtf(1.0f + (float)cnt[i]);
}

__global__ void scan_kernel(const int* __restrict__ cnt, int* __restrict__ row_ptr) {
    __shared__ int lds[1024];
    __shared__ int base_s;
    int tid = threadIdx.x;
    if (tid == 0) base_s = 0;
    __syncthreads();
    for (int chunk = 0; chunk < NN; chunk += 1024) {
        int i = chunk + tid;
        int v = (i < NN) ? cnt[i] : 0;
        lds[tid] = v;
        __syncthreads();
        for (int off = 1; off < 1024; off <<= 1) {
            int t = (tid >= off) ? lds[tid - off] : 0;
            __syncthreads();
            lds[tid] += t;
            __syncthreads();
        }
        int incl = lds[tid];
        int base = base_s;
        if (i < NN) row_ptr[i] = base + incl - v;
        __syncthreads();
        if (tid == 1023) base_s = base + incl;
        __syncthreads();
    }
    if (tid == 0) row_ptr[NN] = base_s;
}

__global__ void scatter_kernel(const void* __restrict__ eidx, const int* __restrict__ flags,
                               const int* __restrict__ row_ptr, int* __restrict__ fill,
                               const float* __restrict__ dinv,
                               int* __restrict__ col, float* __restrict__ val) {
    int e = blockIdx.x * blockDim.x + threadIdx.x;
    if (e < NE) {
        int is64 = flags[1];
        int s = edge_at(eidx, is64, (size_t)e);
        int d = edge_at(eidx, is64, (size_t)NE + e);
        int pos = row_ptr[d] + atomicAdd(&fill[d], 1);
        col[pos] = s;
        val[pos] = dinv[d] * dinv[s];
    }
}

// ---------------- x0 = relu(x @ W1 + b1); x0 fp32, h0 bf16 ----------------

__global__ __launch_bounds__(256) void x0_kernel(const void* __restrict__ x,
                                                 const void* __restrict__ W1,
                                                 const void* __restrict__ b1,
                                                 const int* __restrict__ flags,
                                                 float* __restrict__ x0,
                                                 unsigned short* __restrict__ h0) {
    __shared__ float lw[FIN * HD];  // 32 KiB
    int isf = flags[0];
    int tid = threadIdx.x;
    for (int i = tid; i < FIN * HD; i += 256) lw[i] = fin_at(W1, isf, i);
    __syncthreads();
    int row = blockIdx.x * 4 + (tid >> 6);
    int lane = tid & 63;
    if (row >= NN) return;
    float xa = fin_at(x, isf, (size_t)row * FIN + lane);
    float xb = fin_at(x, isf, (size_t)row * FIN + 64 + lane);
    float acc = fin_at(b1, isf, lane);
    #pragma unroll 8
    for (int k = 0; k < 64; k++) {
        float xv = __shfl(xa, k, 64);
        acc += xv * lw[k * HD + lane];
    }
    #pragma unroll 8
    for (int k = 0; k < 64; k++) {
        float xv = __shfl(xb, k, 64);
        acc += xv * lw[(64 + k) * HD + lane];
    }
    float r = fmaxf(acc, 0.0f);
    x0[(size_t)row * HD + lane] = r;
    h0[(size_t)row * HD + lane] = f2bf(r);
}

// ---------------- fused layer: h_out = relu((1-b)*s + b*(s@Wl)), s = 0.9*A@h + 0.1*x0 ----
// block = 4 waves x 4 rows/wave = 16 rows. h in bf16; gather = 128B coalesced row reads.

__global__ __launch_bounds__(256) void layer_fused(const int* __restrict__ row_ptr,
                                                   const int* __restrict__ col,
                                                   const float* __restrict__ val,
                                                   const float* __restrict__ dinv,
                                                   const unsigned short* __restrict__ h_in,
                                                   const float* __restrict__ x0,
                                                   unsigned short* __restrict__ h_out,
                                                   const void* __restrict__ convW, int layer,
                                                   const int* __restrict__ flags, float beta) {
    __shared__ float lw[HD * HD];  // W_l fp32, 16 KiB
    int isf = flags[0];
    size_t wbase = (size_t)layer * HD * HD;
    int tid = threadIdx.x;
    for (int i = tid; i < HD * HD; i += 256) lw[i] = fin_at(convW, isf, wbase + i);
    __syncthreads();

    int wave = tid >> 6, lane = tid & 63;
    int row0 = blockIdx.x * RPB + wave * RPW;

    float sacc[RPW];
    #pragma unroll
    for (int r = 0; r < RPW; r++) {
        int row = row0 + r;
        if (row >= NN) { sacc[r] = 0.0f; continue; }
        float di = dinv[row];
        float a = di * di * bf2f(h_in[(size_t)row * HD + lane]);  // self-loop
        int start = row_ptr[row], end = row_ptr[row + 1];
        for (int base = start; base < end; base += 64) {
            int idx = base + lane;
            int cc = 0; float vv = 0.0f;
            if (idx < end) { cc = col[idx]; vv = val[idx]; }
            int n = min(64, end - base);
            int j = 0;
            for (; j + 4 <= n; j += 4) {
                int c0 = __shfl(cc, j, 64),     c1 = __shfl(cc, j + 1, 64);
                int c2 = __shfl(cc, j + 2, 64), c3 = __shfl(cc, j + 3, 64);
                float w0 = __shfl(vv, j, 64),     w1 = __shfl(vv, j + 1, 64);
                float w2 = __shfl(vv, j + 2, 64), w3 = __shfl(vv, j + 3, 64);
                unsigned short u0 = h_in[(size_t)c0 * HD + lane];
                unsigned short u1 = h_in[(size_t)c1 * HD + lane];
                unsigned short u2 = h_in[(size_t)c2 * HD + lane];
                unsigned short u3 = h_in[(size_t)c3 * HD + lane];
                a += w0 * bf2f(u0); a += w1 * bf2f(u1);
                a += w2 * bf2f(u2); a += w3 * bf2f(u3);
            }
            for (; j < n; j++) {
                int c = __shfl(cc, j, 64);
                float w = __shfl(vv, j, 64);
                a += w * bf2f(h_in[(size_t)c * HD + lane]);
            }
        }
        sacc[r] = 0.9f * a + 0.1f * x0[(size_t)row * HD + lane];
    }

    // dense: d = s @ Wl ; s packed 2-rows-per-dword bf16, broadcast via shfl
    unsigned int p01 = ((unsigned int)f2bf(sacc[0]) << 16) | f2bf(sacc[1]);
    unsigned int p23 = ((unsigned int)f2bf(sacc[2]) << 16) | f2bf(sacc[3]);
    float d0 = 0.0f, d1 = 0.0f, d2 = 0.0f, d3 = 0.0f;
    #pragma unroll 8
    for (int k = 0; k < 64; k++) {
        float w = lw[k * HD + lane];
        unsigned int b01 = __shfl(p01, k, 64);
        unsigned int b23 = __shfl(p23, k, 64);
        union { unsigned int i; float f; } f0, f1, f2, f3;
        f0.i = b01 & 0xFFFF0000u; f1.i = b01 << 16;
        f2.i = b23 & 0xFFFF0000u; f3.i = b23 << 16;
        d0 += f0.f * w; d1 += f1.f * w;
        d2 += f2.f * w; d3 += f3.f * w;
    }

    float dd[RPW] = {d0, d1, d2, d3};
    float omb = 1.0f - beta;
    #pragma unroll
    for (int r = 0; r < RPW; r++) {
        int row = row0 + r;
        if (row >= NN) continue;
        float res = omb * sacc[r] + beta * dd[r];
        h_out[(size_t)row * HD + lane] = f2bf(fmaxf(res, 0.0f));
    }
}

// ---------------- out = log_softmax(h @ W2 + b2) ----------------

__global__ __launch_bounds__(256) void out_kernel(const unsigned short* __restrict__ h,
                                                  const void* __restrict__ W2,
                                                  const void* __restrict__ b2,
                                                  const int* __restrict__ flags,
                                                  void* __restrict__ out) {
    __shared__ float lw[HD * 64];  // padded [64][64], cols >= 47 zero
    int isf = flags[0];
    int tid = threadIdx.x;
    for (int i = tid; i < HD * 64; i += 256) {
        int k = i >> 6, j = i & 63;
        lw[i] = (j < NC) ? fin_at(W2, isf, (size_t)k * NC + j) : 0.0f;
    }
    __syncthreads();
    int row = blockIdx.x * 4 + (tid >> 6);
    int lane = tid & 63;
    if (row >= NN) return;
    float hv = bf2f(h[(size_t)row * HD + lane]);
    float acc = (lane < NC) ? fin_at(b2, isf, lane) : 0.0f;
    #pragma unroll 8
    for (int k = 0; k < 64; k++) {
        float hk = __shfl(hv, k, 64);
        acc += hk * lw[k * 64 + lane];
    }
    float mv = (lane < NC) ? acc : -1e30f;
    for (int off = 32; off > 0; off >>= 1) mv = fmaxf(mv, __shfl_xor(mv, off, 64));
    float ex = (lane < NC) ? expf(acc - mv) : 0.0f;
    float se = ex;
    for (int off = 32; off > 0; off >>= 1) se += __shfl_xor(se, off, 64);
    float res = acc - mv - logf(se);
    if (lane < NC) {
        size_t oi = (size_t)row * NC + lane;
        if (isf) ((float*)out)[oi] = res;
        else     ((__hip_bfloat16*)out)[oi] = __float2bfloat16(res);
    }
}

// ---------------- host ----------------

static inline size_t align256(size_t x) { return (x + 255) & ~(size_t)255; }

extern "C" void kernel_launch(void* const* d_in, const int* in_sizes, int n_in,
                              void* d_out, int out_size, void* d_ws, size_t ws_size,
                              hipStream_t stream) {
    const void* x     = d_in[0];
    const void* eidx  = d_in[1];
    const void* W1    = d_in[2];
    const void* b1    = d_in[3];
    const void* convW = d_in[4];
    const void* W2    = d_in[5];
    const void* b2    = d_in[6];

    char* p = (char*)d_ws;
    size_t off = 0;
    auto alloc = [&](size_t bytes) { void* r = p + off; off += align256(bytes); return r; };
    int*            flags   = (int*)alloc(256);
    int*            cnt     = (int*)alloc((size_t)NN * 4);
    int*            fill    = (int*)alloc((size_t)NN * 4);
    int*            row_ptr = (int*)alloc((size_t)(NN + 1) * 4);
    float*          dinv    = (float*)alloc((size_t)NN * 4);
    int*            col     = (int*)alloc((size_t)NE * 4);
    float*          val     = (float*)alloc((size_t)NE * 4);
    float*          x0      = (float*)alloc((size_t)NN * HD * 4);
    unsigned short* hA      = (unsigned short*)alloc((size_t)NN * HD * 2);
    unsigned short* hB      = (unsigned short*)alloc((size_t)NN * HD * 2);

    detect_kernel<<<1, 64, 0, stream>>>(x, eidx, flags);

    hipMemsetAsync(cnt, 0, (size_t)NN * 4, stream);
    hipMemsetAsync(fill, 0, (size_t)NN * 4, stream);
    count_kernel<<<(NE + 255) / 256, 256, 0, stream>>>(eidx, flags, cnt);
    dinv_kernel<<<(NN + 255) / 256, 256, 0, stream>>>(cnt, dinv);
    scan_kernel<<<1, 1024, 0, stream>>>(cnt, row_ptr);
    scatter_kernel<<<(NE + 255) / 256, 256, 0, stream>>>(eidx, flags, row_ptr, fill, dinv, col, val);

    x0_kernel<<<(NN + 3) / 4, 256, 0, stream>>>(x, W1, b1, flags, x0, hA);

    int fb = (NN + RPB - 1) / RPB;  // 6250 blocks
    unsigned short* hin = hA;
    unsigned short* hout = hB;
    for (int l = 0; l < NL; l++) {
        float beta = logf(0.5f / (float)(l + 1) + 1.0f);
        layer_fused<<<fb, 256, 0, stream>>>(row_ptr, col, val, dinv, hin, x0, hout,
                                            convW, l, flags, beta);
        unsigned short* t = hin; hin = hout; hout = t;
    }
    out_kernel<<<(NN + 3) / 4, 256, 0, stream>>>(hin, W2, b2, flags, (void*)d_out);
}

// Round 4
// 8875.934 us; speedup vs baseline: 2.1883x; 1.0314x over previous
//
#include <hip/hip_runtime.h>
#include <hip/hip_bf16.h>
#include <math.h>

#define NN 100000
#define NE 3200000
#define FIN 128
#define HD 64
#define NL 64
#define NC 47
#define RPW 4               // rows per wave (packed dense)
#define WPB 4               // waves per block
#define RPB (RPW * WPB)     // rows per block = 16

// ---------------- helpers ----------------

__device__ __forceinline__ float bf2f(unsigned short u) {
    union { unsigned int i; float f; } v; v.i = ((unsigned int)u) << 16; return v.f;
}
__device__ __forceinline__ unsigned short f2bf(float f) {
    __hip_bfloat16 h = __float2bfloat16(f);   // RNE
    return *reinterpret_cast<unsigned short*>(&h);
}
__device__ __forceinline__ float fin_at(const void* p, int isf32, size_t i) {
    return isf32 ? ((const float*)p)[i]
                 : __bfloat162float(((const __hip_bfloat16*)p)[i]);
}
__device__ __forceinline__ int edge_at(const void* p, int is64, size_t i) {
    return is64 ? (int)((const long long*)p)[i] : ((const int*)p)[i];
}

// ---------------- runtime dtype detection ----------------
// flags[0]: 1 = float inputs are fp32, 0 = bf16
// flags[1]: 1 = edge_index is int64, 0 = int32

__global__ void detect_kernel(const void* __restrict__ x, const void* __restrict__ eidx,
                              int* __restrict__ flags) {
    if (threadIdx.x == 0 && blockIdx.x == 0) {
        const unsigned short* u = (const unsigned short*)x;
        int sane = 0;
        for (int i = 0; i < 64; i++) {
            unsigned short v = u[2 * i];
            int e = (v >> 7) & 0xFF;
            if ((v & 0x7FFF) == 0 || (e >= 90 && e <= 141)) sane++;
        }
        flags[0] = (sane >= 48) ? 0 : 1;
        const int* e32 = (const int*)eidx;
        int nz = 0;
        for (int i = 0; i < 64; i++) if (e32[2 * i + 1] != 0) nz++;
        flags[1] = (nz == 0) ? 1 : 0;
    }
}

// ---------------- CSR build ----------------

__global__ void count_kernel(const void* __restrict__ eidx, const int* __restrict__ flags,
                             int* __restrict__ cnt) {
    int e = blockIdx.x * blockDim.x + threadIdx.x;
    if (e < NE) {
        int d = edge_at(eidx, flags[1], (size_t)NE + e);
        atomicAdd(&cnt[d], 1);
    }
}

__global__ void dinv_kernel(const int* __restrict__ cnt, float* __restrict__ dinv) {
    int i = blockIdx.x * blockDim.x + threadIdx.x;
    if (i < NN) dinv[i] = rsqrtf(1.0f + (float)cnt[i]);
}

__global__ void scan_kernel(const int* __restrict__ cnt, int* __restrict__ row_ptr) {
    __shared__ int lds[1024];
    __shared__ int base_s;
    int tid = threadIdx.x;
    if (tid == 0) base_s = 0;
    __syncthreads();
    for (int chunk = 0; chunk < NN; chunk += 1024) {
        int i = chunk + tid;
        int v = (i < NN) ? cnt[i] : 0;
        lds[tid] = v;
        __syncthreads();
        for (int off = 1; off < 1024; off <<= 1) {
            int t = (tid >= off) ? lds[tid - off] : 0;
            __syncthreads();
            lds[tid] += t;
            __syncthreads();
        }
        int incl = lds[tid];
        int base = base_s;
        if (i < NN) row_ptr[i] = base + incl - v;
        __syncthreads();
        if (tid == 1023) base_s = base + incl;
        __syncthreads();
    }
    if (tid == 0) row_ptr[NN] = base_s;
}

__global__ void scatter_kernel(const void* __restrict__ eidx, const int* __restrict__ flags,
                               const int* __restrict__ row_ptr, int* __restrict__ fill,
                               const float* __restrict__ dinv,
                               int* __restrict__ col, float* __restrict__ val) {
    int e = blockIdx.x * blockDim.x + threadIdx.x;
    if (e < NE) {
        int is64 = flags[1];
        int s = edge_at(eidx, is64, (size_t)e);
        int d = edge_at(eidx, is64, (size_t)NE + e);
        int pos = row_ptr[d] + atomicAdd(&fill[d], 1);
        col[pos] = s;
        val[pos] = dinv[d] * dinv[s];
    }
}

// ---------------- x0 = relu(x @ W1 + b1); 4 rows/wave packed ----------------

__global__ __launch_bounds__(256) void x0_kernel(const void* __restrict__ x,
                                                 const void* __restrict__ W1,
                                                 const void* __restrict__ b1,
                                                 const int* __restrict__ flags,
                                                 float* __restrict__ x0,
                                                 unsigned short* __restrict__ h0) {
    __shared__ float lw[FIN * HD];  // 32 KiB
    int isf = flags[0];
    int tid = threadIdx.x;
    for (int i = tid; i < FIN * HD; i += 256) lw[i] = fin_at(W1, isf, i);
    __syncthreads();
    int wave = tid >> 6, lane = tid & 63;
    int row0 = blockIdx.x * RPB + wave * RPW;
    if (row0 >= NN) return;
    // pack x[row_r][lane] (low 64 feats) and x[row_r][64+lane] (high 64)
    unsigned int pa01, pa23, pb01, pb23;
    {
        unsigned short a0 = f2bf(fin_at(x, isf, (size_t)(row0 + 0) * FIN + lane));
        unsigned short a1 = f2bf(fin_at(x, isf, (size_t)(row0 + 1) * FIN + lane));
        unsigned short a2 = f2bf(fin_at(x, isf, (size_t)(row0 + 2) * FIN + lane));
        unsigned short a3 = f2bf(fin_at(x, isf, (size_t)(row0 + 3) * FIN + lane));
        unsigned short c0 = f2bf(fin_at(x, isf, (size_t)(row0 + 0) * FIN + 64 + lane));
        unsigned short c1 = f2bf(fin_at(x, isf, (size_t)(row0 + 1) * FIN + 64 + lane));
        unsigned short c2 = f2bf(fin_at(x, isf, (size_t)(row0 + 2) * FIN + 64 + lane));
        unsigned short c3 = f2bf(fin_at(x, isf, (size_t)(row0 + 3) * FIN + 64 + lane));
        pa01 = ((unsigned int)a0 << 16) | a1;  pa23 = ((unsigned int)a2 << 16) | a3;
        pb01 = ((unsigned int)c0 << 16) | c1;  pb23 = ((unsigned int)c2 << 16) | c3;
    }
    float bias = fin_at(b1, isf, lane);
    float d0 = bias, d1 = bias, d2 = bias, d3 = bias;
    #pragma unroll 8
    for (int k = 0; k < 64; k++) {
        float w = lw[k * HD + lane];
        unsigned int b01 = __shfl(pa01, k, 64);
        unsigned int b23 = __shfl(pa23, k, 64);
        union { unsigned int i; float f; } f0, f1, f2, f3;
        f0.i = b01 & 0xFFFF0000u; f1.i = b01 << 16;
        f2.i = b23 & 0xFFFF0000u; f3.i = b23 << 16;
        d0 += f0.f * w; d1 += f1.f * w; d2 += f2.f * w; d3 += f3.f * w;
    }
    #pragma unroll 8
    for (int k = 0; k < 64; k++) {
        float w = lw[(64 + k) * HD + lane];
        unsigned int b01 = __shfl(pb01, k, 64);
        unsigned int b23 = __shfl(pb23, k, 64);
        union { unsigned int i; float f; } f0, f1, f2, f3;
        f0.i = b01 & 0xFFFF0000u; f1.i = b01 << 16;
        f2.i = b23 & 0xFFFF0000u; f3.i = b23 << 16;
        d0 += f0.f * w; d1 += f1.f * w; d2 += f2.f * w; d3 += f3.f * w;
    }
    float dd[RPW] = {d0, d1, d2, d3};
    #pragma unroll
    for (int r = 0; r < RPW; r++) {
        int row = row0 + r;
        if (row >= NN) continue;
        float v = fmaxf(dd[r], 0.0f);
        x0[(size_t)row * HD + lane] = v;
        h0[(size_t)row * HD + lane] = f2bf(v);
    }
}

// ---------------- fused layer: h_out = relu((1-b)*s + b*(s@Wl)), s = 0.9*A@h + 0.1*x0 ----
// block = 4 waves x 4 rows/wave; gather 8-unrolled for MLP.

__global__ __launch_bounds__(256) void layer_fused(const int* __restrict__ row_ptr,
                                                   const int* __restrict__ col,
                                                   const float* __restrict__ val,
                                                   const float* __restrict__ dinv,
                                                   const unsigned short* __restrict__ h_in,
                                                   const float* __restrict__ x0,
                                                   unsigned short* __restrict__ h_out,
                                                   const void* __restrict__ convW, int layer,
                                                   const int* __restrict__ flags, float beta) {
    __shared__ float lw[HD * HD];  // W_l fp32, 16 KiB
    int isf = flags[0];
    size_t wbase = (size_t)layer * HD * HD;
    int tid = threadIdx.x;
    for (int i = tid; i < HD * HD; i += 256) lw[i] = fin_at(convW, isf, wbase + i);
    __syncthreads();

    int wave = tid >> 6, lane = tid & 63;
    int row0 = blockIdx.x * RPB + wave * RPW;

    float sacc[RPW];
    #pragma unroll
    for (int r = 0; r < RPW; r++) {
        int row = row0 + r;
        if (row >= NN) { sacc[r] = 0.0f; continue; }
        float di = dinv[row];
        float a = di * di * bf2f(h_in[(size_t)row * HD + lane]);  // self-loop
        int start = row_ptr[row], end = row_ptr[row + 1];
        for (int base = start; base < end; base += 64) {
            int idx = base + lane;
            int cc = 0; float vv = 0.0f;
            if (idx < end) { cc = col[idx]; vv = val[idx]; }
            int n = min(64, end - base);
            int j = 0;
            for (; j + 8 <= n; j += 8) {
                int c0 = __shfl(cc, j, 64),     c1 = __shfl(cc, j + 1, 64);
                int c2 = __shfl(cc, j + 2, 64), c3 = __shfl(cc, j + 3, 64);
                int c4 = __shfl(cc, j + 4, 64), c5 = __shfl(cc, j + 5, 64);
                int c6 = __shfl(cc, j + 6, 64), c7 = __shfl(cc, j + 7, 64);
                float w0 = __shfl(vv, j, 64),     w1 = __shfl(vv, j + 1, 64);
                float w2 = __shfl(vv, j + 2, 64), w3 = __shfl(vv, j + 3, 64);
                float w4 = __shfl(vv, j + 4, 64), w5 = __shfl(vv, j + 5, 64);
                float w6 = __shfl(vv, j + 6, 64), w7 = __shfl(vv, j + 7, 64);
                unsigned short u0 = h_in[(size_t)c0 * HD + lane];
                unsigned short u1 = h_in[(size_t)c1 * HD + lane];
                unsigned short u2 = h_in[(size_t)c2 * HD + lane];
                unsigned short u3 = h_in[(size_t)c3 * HD + lane];
                unsigned short u4 = h_in[(size_t)c4 * HD + lane];
                unsigned short u5 = h_in[(size_t)c5 * HD + lane];
                unsigned short u6 = h_in[(size_t)c6 * HD + lane];
                unsigned short u7 = h_in[(size_t)c7 * HD + lane];
                a += w0 * bf2f(u0); a += w1 * bf2f(u1);
                a += w2 * bf2f(u2); a += w3 * bf2f(u3);
                a += w4 * bf2f(u4); a += w5 * bf2f(u5);
                a += w6 * bf2f(u6); a += w7 * bf2f(u7);
            }
            for (; j < n; j++) {
                int c = __shfl(cc, j, 64);
                float w = __shfl(vv, j, 64);
                a += w * bf2f(h_in[(size_t)c * HD + lane]);
            }
        }
        sacc[r] = 0.9f * a + 0.1f * x0[(size_t)row * HD + lane];
    }

    // dense: d = s @ Wl ; s packed 2-rows-per-dword bf16, broadcast via shfl
    unsigned int p01 = ((unsigned int)f2bf(sacc[0]) << 16) | f2bf(sacc[1]);
    unsigned int p23 = ((unsigned int)f2bf(sacc[2]) << 16) | f2bf(sacc[3]);
    float d0 = 0.0f, d1 = 0.0f, d2 = 0.0f, d3 = 0.0f;
    #pragma unroll 8
    for (int k = 0; k < 64; k++) {
        float w = lw[k * HD + lane];
        unsigned int b01 = __shfl(p01, k, 64);
        unsigned int b23 = __shfl(p23, k, 64);
        union { unsigned int i; float f; } f0, f1, f2, f3;
        f0.i = b01 & 0xFFFF0000u; f1.i = b01 << 16;
        f2.i = b23 & 0xFFFF0000u; f3.i = b23 << 16;
        d0 += f0.f * w; d1 += f1.f * w;
        d2 += f2.f * w; d3 += f3.f * w;
    }

    float dd[RPW] = {d0, d1, d2, d3};
    float omb = 1.0f - beta;
    #pragma unroll
    for (int r = 0; r < RPW; r++) {
        int row = row0 + r;
        if (row >= NN) continue;
        float res = omb * sacc[r] + beta * dd[r];
        h_out[(size_t)row * HD + lane] = f2bf(fmaxf(res, 0.0f));
    }
}

// ---------------- out = log_softmax(h @ W2 + b2) ----------------

__global__ __launch_bounds__(256) void out_kernel(const unsigned short* __restrict__ h,
                                                  const void* __restrict__ W2,
                                                  const void* __restrict__ b2,
                                                  const int* __restrict__ flags,
                                                  void* __restrict__ out) {
    __shared__ float lw[HD * 64];  // padded [64][64], cols >= 47 zero
    int isf = flags[0];
    int tid = threadIdx.x;
    for (int i = tid; i < HD * 64; i += 256) {
        int k = i >> 6, j = i & 63;
        lw[i] = (j < NC) ? fin_at(W2, isf, (size_t)k * NC + j) : 0.0f;
    }
    __syncthreads();
    int row = blockIdx.x * 4 + (tid >> 6);
    int lane = tid & 63;
    if (row >= NN) return;
    float hv = bf2f(h[(size_t)row * HD + lane]);
    float acc = (lane < NC) ? fin_at(b2, isf, lane) : 0.0f;
    #pragma unroll 8
    for (int k = 0; k < 64; k++) {
        float hk = __shfl(hv, k, 64);
        acc += hk * lw[k * 64 + lane];
    }
    float mv = (lane < NC) ? acc : -1e30f;
    for (int off = 32; off > 0; off >>= 1) mv = fmaxf(mv, __shfl_xor(mv, off, 64));
    float ex = (lane < NC) ? expf(acc - mv) : 0.0f;
    float se = ex;
    for (int off = 32; off > 0; off >>= 1) se += __shfl_xor(se, off, 64);
    float res = acc - mv - logf(se);
    if (lane < NC) {
        size_t oi = (size_t)row * NC + lane;
        if (isf) ((float*)out)[oi] = res;
        else     ((__hip_bfloat16*)out)[oi] = __float2bfloat16(res);
    }
}

// ---------------- host ----------------

static inline size_t align256(size_t x) { return (x + 255) & ~(size_t)255; }

extern "C" void kernel_launch(void* const* d_in, const int* in_sizes, int n_in,
                              void* d_out, int out_size, void* d_ws, size_t ws_size,
                              hipStream_t stream) {
    const void* x     = d_in[0];
    const void* eidx  = d_in[1];
    const void* W1    = d_in[2];
    const void* b1    = d_in[3];
    const void* convW = d_in[4];
    const void* W2    = d_in[5];
    const void* b2    = d_in[6];

    char* p = (char*)d_ws;
    size_t off = 0;
    auto alloc = [&](size_t bytes) { void* r = p + off; off += align256(bytes); return r; };
    int*            flags   = (int*)alloc(256);
    int*            cnt     = (int*)alloc((size_t)NN * 4);
    int*            fill    = (int*)alloc((size_t)NN * 4);
    int*            row_ptr = (int*)alloc((size_t)(NN + 1) * 4);
    float*          dinv    = (float*)alloc((size_t)NN * 4);
    int*            col     = (int*)alloc((size_t)NE * 4);
    float*          val     = (float*)alloc((size_t)NE * 4);
    float*          x0      = (float*)alloc((size_t)NN * HD * 4);
    unsigned short* hA      = (unsigned short*)alloc((size_t)NN * HD * 2);
    unsigned short* hB      = (unsigned short*)alloc((size_t)NN * HD * 2);

    detect_kernel<<<1, 64, 0, stream>>>(x, eidx, flags);

    hipMemsetAsync(cnt, 0, (size_t)NN * 4, stream);
    hipMemsetAsync(fill, 0, (size_t)NN * 4, stream);
    count_kernel<<<(NE + 255) / 256, 256, 0, stream>>>(eidx, flags, cnt);
    dinv_kernel<<<(NN + 255) / 256, 256, 0, stream>>>(cnt, dinv);
    scan_kernel<<<1, 1024, 0, stream>>>(cnt, row_ptr);
    scatter_kernel<<<(NE + 255) / 256, 256, 0, stream>>>(eidx, flags, row_ptr, fill, dinv, col, val);

    int fb = (NN + RPB - 1) / RPB;  // 6250 blocks
    x0_kernel<<<fb, 256, 0, stream>>>(x, W1, b1, flags, x0, hA);

    unsigned short* hin = hA;
    unsigned short* hout = hB;
    for (int l = 0; l < NL; l++) {
        float beta = logf(0.5f / (float)(l + 1) + 1.0f);
        layer_fused<<<fb, 256, 0, stream>>>(row_ptr, col, val, dinv, hin, x0, hout,
                                            convW, l, flags, beta);
        unsigned short* t = hin; hin = hout; hout = t;
    }
    out_kernel<<<(NN + 3) / 4, 256, 0, stream>>>(hin, W2, b2, flags, (void*)d_out);
}

// Round 5
// 7906.341 us; speedup vs baseline: 2.4567x; 1.1226x over previous
//
#include <hip/hip_runtime.h>
#include <hip/hip_bf16.h>
#include <math.h>

#define NN 100000
#define NE 3200000
#define FIN 128
#define HD 64
#define NL 64
#define NC 47
#define RPW 4               // rows per wave (packed dense)
#define WPB 4               // waves per block
#define RPB (RPW * WPB)     // rows per block = 16

#define SEGSH 13            // segment = 8192 nodes (1 MiB of bf16 h) for L2 locality
#define NSEG 13             // ceil(100000 / 8192)
#define NKEY (NN * NSEG)    // 1.3M (dst, seg) keys
#define KB ((NKEY + 1023) / 1024)   // scan blocks

// ---------------- helpers ----------------

__device__ __forceinline__ float bf2f(unsigned short u) {
    union { unsigned int i; float f; } v; v.i = ((unsigned int)u) << 16; return v.f;
}
__device__ __forceinline__ unsigned short f2bf(float f) {
    __hip_bfloat16 h = __float2bfloat16(f);   // RNE
    return *reinterpret_cast<unsigned short*>(&h);
}
__device__ __forceinline__ float fin_at(const void* p, int isf32, size_t i) {
    return isf32 ? ((const float*)p)[i]
                 : __bfloat162float(((const __hip_bfloat16*)p)[i]);
}
__device__ __forceinline__ int edge_at(const void* p, int is64, size_t i) {
    return is64 ? (int)((const long long*)p)[i] : ((const int*)p)[i];
}

// ---------------- runtime dtype detection ----------------
// flags[0]: 1 = float inputs are fp32, 0 = bf16
// flags[1]: 1 = edge_index is int64, 0 = int32

__global__ void detect_kernel(const void* __restrict__ x, const void* __restrict__ eidx,
                              int* __restrict__ flags) {
    if (threadIdx.x == 0 && blockIdx.x == 0) {
        const unsigned short* u = (const unsigned short*)x;
        int sane = 0;
        for (int i = 0; i < 64; i++) {
            unsigned short v = u[2 * i];
            int e = (v >> 7) & 0xFF;
            if ((v & 0x7FFF) == 0 || (e >= 90 && e <= 141)) sane++;
        }
        flags[0] = (sane >= 48) ? 0 : 1;
        const int* e32 = (const int*)eidx;
        int nz = 0;
        for (int i = 0; i < 64; i++) if (e32[2 * i + 1] != 0) nz++;
        flags[1] = (nz == 0) ? 1 : 0;
    }
}

// ---------------- segmented-CSR build ----------------
// key = dst*NSEG + (src>>SEGSH); edges of a row end up contiguous AND
// segment-sorted -> whole-machine sweeps h left-to-right (L2-resident window).

__global__ void key_count(const void* __restrict__ eidx, const int* __restrict__ flags,
                          int* __restrict__ cnt) {
    int e = blockIdx.x * blockDim.x + threadIdx.x;
    if (e < NE) {
        int is64 = flags[1];
        int s = edge_at(eidx, is64, (size_t)e);
        int d = edge_at(eidx, is64, (size_t)NE + e);
        atomicAdd(&cnt[d * NSEG + (s >> SEGSH)], 1);
    }
}

// level-1: per-1024-chunk totals
__global__ __launch_bounds__(1024) void scan_reduce(const int* __restrict__ cnt,
                                                    int* __restrict__ bsum) {
    __shared__ int lds[1024];
    int tid = threadIdx.x;
    int i = blockIdx.x * 1024 + tid;
    lds[tid] = (i < NKEY) ? cnt[i] : 0;
    __syncthreads();
    for (int off = 512; off > 0; off >>= 1) {
        if (tid < off) lds[tid] += lds[tid + off];
        __syncthreads();
    }
    if (tid == 0) bsum[blockIdx.x] = lds[0];
}

// level-2: single-block chunked exclusive scan of bsum[0..KB); total -> *total_out
__global__ __launch_bounds__(1024) void scan_mid(int* __restrict__ bsum, int* __restrict__ total_out) {
    __shared__ int lds[1024];
    __shared__ int base_s;
    int tid = threadIdx.x;
    if (tid == 0) base_s = 0;
    __syncthreads();
    for (int chunk = 0; chunk < KB; chunk += 1024) {
        int i = chunk + tid;
        int v = (i < KB) ? bsum[i] : 0;
        lds[tid] = v;
        __syncthreads();
        for (int off = 1; off < 1024; off <<= 1) {
            int t = (tid >= off) ? lds[tid - off] : 0;
            __syncthreads();
            lds[tid] += t;
            __syncthreads();
        }
        int incl = lds[tid];
        int base = base_s;
        if (i < KB) bsum[i] = base + incl - v;   // exclusive
        __syncthreads();
        if (tid == 1023) base_s = base + incl;
        __syncthreads();
    }
    if (tid == 0) *total_out = base_s;           // == NE
}

// level-3: exclusive scan within each chunk + block offset -> keyptr
__global__ __launch_bounds__(1024) void scan_final(const int* __restrict__ cnt,
                                                   const int* __restrict__ bsum,
                                                   int* __restrict__ keyptr) {
    __shared__ int lds[1024];
    int tid = threadIdx.x;
    int i = blockIdx.x * 1024 + tid;
    int v = (i < NKEY) ? cnt[i] : 0;
    lds[tid] = v;
    __syncthreads();
    for (int off = 1; off < 1024; off <<= 1) {
        int t = (tid >= off) ? lds[tid - off] : 0;
        __syncthreads();
        lds[tid] += t;
        __syncthreads();
    }
    if (i < NKEY) keyptr[i] = bsum[blockIdx.x] + lds[tid] - v;
}

__global__ void dinv_kernel(const int* __restrict__ keyptr, float* __restrict__ dinv) {
    int i = blockIdx.x * blockDim.x + threadIdx.x;
    if (i < NN) {
        int deg = keyptr[(i + 1) * NSEG] - keyptr[i * NSEG];
        dinv[i] = rsqrtf(1.0f + (float)deg);   // +1 for self-loop
    }
}

__global__ void scatter_kernel(const void* __restrict__ eidx, const int* __restrict__ flags,
                               const int* __restrict__ keyptr, int* __restrict__ fill,
                               int* __restrict__ col) {
    int e = blockIdx.x * blockDim.x + threadIdx.x;
    if (e < NE) {
        int is64 = flags[1];
        int s = edge_at(eidx, is64, (size_t)e);
        int d = edge_at(eidx, is64, (size_t)NE + e);
        int key = d * NSEG + (s >> SEGSH);
        int pos = keyptr[key] + atomicAdd(&fill[key], 1);
        col[pos] = s;
    }
}

// ---------------- x0 = relu(x @ W1 + b1); x0 fp32, g0 = dinv*x0 bf16 ----------------

__global__ __launch_bounds__(256) void x0_kernel(const void* __restrict__ x,
                                                 const void* __restrict__ W1,
                                                 const void* __restrict__ b1,
                                                 const int* __restrict__ flags,
                                                 const float* __restrict__ dinv,
                                                 float* __restrict__ x0,
                                                 unsigned short* __restrict__ g0) {
    __shared__ float lw[FIN * HD];  // 32 KiB
    int isf = flags[0];
    int tid = threadIdx.x;
    for (int i = tid; i < FIN * HD; i += 256) lw[i] = fin_at(W1, isf, i);
    __syncthreads();
    int wave = tid >> 6, lane = tid & 63;
    int row0 = blockIdx.x * RPB + wave * RPW;
    if (row0 >= NN) return;
    unsigned int pa01, pa23, pb01, pb23;
    {
        unsigned short a0 = f2bf(fin_at(x, isf, (size_t)(row0 + 0) * FIN + lane));
        unsigned short a1 = f2bf(fin_at(x, isf, (size_t)(row0 + 1) * FIN + lane));
        unsigned short a2 = f2bf(fin_at(x, isf, (size_t)(row0 + 2) * FIN + lane));
        unsigned short a3 = f2bf(fin_at(x, isf, (size_t)(row0 + 3) * FIN + lane));
        unsigned short c0 = f2bf(fin_at(x, isf, (size_t)(row0 + 0) * FIN + 64 + lane));
        unsigned short c1 = f2bf(fin_at(x, isf, (size_t)(row0 + 1) * FIN + 64 + lane));
        unsigned short c2 = f2bf(fin_at(x, isf, (size_t)(row0 + 2) * FIN + 64 + lane));
        unsigned short c3 = f2bf(fin_at(x, isf, (size_t)(row0 + 3) * FIN + 64 + lane));
        pa01 = ((unsigned int)a0 << 16) | a1;  pa23 = ((unsigned int)a2 << 16) | a3;
        pb01 = ((unsigned int)c0 << 16) | c1;  pb23 = ((unsigned int)c2 << 16) | c3;
    }
    float bias = fin_at(b1, isf, lane);
    float d0 = bias, d1 = bias, d2 = bias, d3 = bias;
    #pragma unroll 8
    for (int k = 0; k < 64; k++) {
        float w = lw[k * HD + lane];
        unsigned int b01 = __shfl(pa01, k, 64);
        unsigned int b23 = __shfl(pa23, k, 64);
        union { unsigned int i; float f; } f0, f1, f2, f3;
        f0.i = b01 & 0xFFFF0000u; f1.i = b01 << 16;
        f2.i = b23 & 0xFFFF0000u; f3.i = b23 << 16;
        d0 += f0.f * w; d1 += f1.f * w; d2 += f2.f * w; d3 += f3.f * w;
    }
    #pragma unroll 8
    for (int k = 0; k < 64; k++) {
        float w = lw[(64 + k) * HD + lane];
        unsigned int b01 = __shfl(pb01, k, 64);
        unsigned int b23 = __shfl(pb23, k, 64);
        union { unsigned int i; float f; } f0, f1, f2, f3;
        f0.i = b01 & 0xFFFF0000u; f1.i = b01 << 16;
        f2.i = b23 & 0xFFFF0000u; f3.i = b23 << 16;
        d0 += f0.f * w; d1 += f1.f * w; d2 += f2.f * w; d3 += f3.f * w;
    }
    float dd[RPW] = {d0, d1, d2, d3};
    #pragma unroll
    for (int r = 0; r < RPW; r++) {
        int row = row0 + r;
        if (row >= NN) continue;
        float v = fmaxf(dd[r], 0.0f);
        x0[(size_t)row * HD + lane] = v;
        g0[(size_t)row * HD + lane] = f2bf(dinv[row] * v);
    }
}

// ---------------- fused layer ----------------
// p[d] = dinv[d]*(sum_{s in N(d)} g[s] + g[d]);  s = 0.9p + 0.1x0
// h = relu((1-b)s + b(s@Wl));  store g_out = dinv*h (bf16)

__global__ __launch_bounds__(256) void layer_fused(const int* __restrict__ keyptr,
                                                   const int* __restrict__ col,
                                                   const float* __restrict__ dinv,
                                                   const unsigned short* __restrict__ g_in,
                                                   const float* __restrict__ x0,
                                                   unsigned short* __restrict__ g_out,
                                                   const void* __restrict__ convW, int layer,
                                                   const int* __restrict__ flags, float beta) {
    __shared__ float lw[HD * HD];  // W_l fp32, 16 KiB
    int isf = flags[0];
    size_t wbase = (size_t)layer * HD * HD;
    int tid = threadIdx.x;
    for (int i = tid; i < HD * HD; i += 256) lw[i] = fin_at(convW, isf, wbase + i);
    __syncthreads();

    int wave = tid >> 6, lane = tid & 63;
    int row0 = blockIdx.x * RPB + wave * RPW;

    float sacc[RPW];
    float dscale[RPW];
    #pragma unroll
    for (int r = 0; r < RPW; r++) {
        int row = row0 + r;
        if (row >= NN) { sacc[r] = 0.0f; dscale[r] = 1.0f; continue; }
        float a = bf2f(g_in[(size_t)row * HD + lane]);  // self-loop: + g[d]
        int start = keyptr[row * NSEG], end = keyptr[(row + 1) * NSEG];
        for (int base = start; base < end; base += 64) {
            int idx = base + lane;
            int cc = (idx < end) ? col[idx] : 0;
            int n = min(64, end - base);
            int j = 0;
            for (; j + 8 <= n; j += 8) {
                int c0 = __shfl(cc, j, 64),     c1 = __shfl(cc, j + 1, 64);
                int c2 = __shfl(cc, j + 2, 64), c3 = __shfl(cc, j + 3, 64);
                int c4 = __shfl(cc, j + 4, 64), c5 = __shfl(cc, j + 5, 64);
                int c6 = __shfl(cc, j + 6, 64), c7 = __shfl(cc, j + 7, 64);
                unsigned short u0 = g_in[(size_t)c0 * HD + lane];
                unsigned short u1 = g_in[(size_t)c1 * HD + lane];
                unsigned short u2 = g_in[(size_t)c2 * HD + lane];
                unsigned short u3 = g_in[(size_t)c3 * HD + lane];
                unsigned short u4 = g_in[(size_t)c4 * HD + lane];
                unsigned short u5 = g_in[(size_t)c5 * HD + lane];
                unsigned short u6 = g_in[(size_t)c6 * HD + lane];
                unsigned short u7 = g_in[(size_t)c7 * HD + lane];
                a += bf2f(u0); a += bf2f(u1); a += bf2f(u2); a += bf2f(u3);
                a += bf2f(u4); a += bf2f(u5); a += bf2f(u6); a += bf2f(u7);
            }
            for (; j < n; j++) {
                int c = __shfl(cc, j, 64);
                a += bf2f(g_in[(size_t)c * HD + lane]);
            }
        }
        float di = dinv[row];
        dscale[r] = di;
        sacc[r] = 0.9f * (di * a) + 0.1f * x0[(size_t)row * HD + lane];
    }

    // dense: d = s @ Wl ; s packed 2-rows-per-dword bf16, broadcast via shfl
    unsigned int p01 = ((unsigned int)f2bf(sacc[0]) << 16) | f2bf(sacc[1]);
    unsigned int p23 = ((unsigned int)f2bf(sacc[2]) << 16) | f2bf(sacc[3]);
    float d0 = 0.0f, d1 = 0.0f, d2 = 0.0f, d3 = 0.0f;
    #pragma unroll 8
    for (int k = 0; k < 64; k++) {
        float w = lw[k * HD + lane];
        unsigned int b01 = __shfl(p01, k, 64);
        unsigned int b23 = __shfl(p23, k, 64);
        union { unsigned int i; float f; } f0, f1, f2, f3;
        f0.i = b01 & 0xFFFF0000u; f1.i = b01 << 16;
        f2.i = b23 & 0xFFFF0000u; f3.i = b23 << 16;
        d0 += f0.f * w; d1 += f1.f * w;
        d2 += f2.f * w; d3 += f3.f * w;
    }

    float dd[RPW] = {d0, d1, d2, d3};
    float omb = 1.0f - beta;
    #pragma unroll
    for (int r = 0; r < RPW; r++) {
        int row = row0 + r;
        if (row >= NN) continue;
        float res = omb * sacc[r] + beta * dd[r];
        g_out[(size_t)row * HD + lane] = f2bf(dscale[r] * fmaxf(res, 0.0f));
    }
}

// ---------------- out = log_softmax(h @ W2 + b2), h = g/dinv ----------------

__global__ __launch_bounds__(256) void out_kernel(const unsigned short* __restrict__ g,
                                                  const float* __restrict__ dinv,
                                                  const void* __restrict__ W2,
                                                  const void* __restrict__ b2,
                                                  const int* __restrict__ flags,
                                                  void* __restrict__ out) {
    __shared__ float lw[HD * 64];  // padded [64][64], cols >= 47 zero
    int isf = flags[0];
    int tid = threadIdx.x;
    for (int i = tid; i < HD * 64; i += 256) {
        int k = i >> 6, j = i & 63;
        lw[i] = (j < NC) ? fin_at(W2, isf, (size_t)k * NC + j) : 0.0f;
    }
    __syncthreads();
    int row = blockIdx.x * 4 + (tid >> 6);
    int lane = tid & 63;
    if (row >= NN) return;
    float hv = bf2f(g[(size_t)row * HD + lane]) / dinv[row];
    float acc = (lane < NC) ? fin_at(b2, isf, lane) : 0.0f;
    #pragma unroll 8
    for (int k = 0; k < 64; k++) {
        float hk = __shfl(hv, k, 64);
        acc += hk * lw[k * 64 + lane];
    }
    float mv = (lane < NC) ? acc : -1e30f;
    for (int off = 32; off > 0; off >>= 1) mv = fmaxf(mv, __shfl_xor(mv, off, 64));
    float ex = (lane < NC) ? expf(acc - mv) : 0.0f;
    float se = ex;
    for (int off = 32; off > 0; off >>= 1) se += __shfl_xor(se, off, 64);
    float res = acc - mv - logf(se);
    if (lane < NC) {
        size_t oi = (size_t)row * NC + lane;
        if (isf) ((float*)out)[oi] = res;
        else     ((__hip_bfloat16*)out)[oi] = __float2bfloat16(res);
    }
}

// ---------------- host ----------------

static inline size_t align256(size_t x) { return (x + 255) & ~(size_t)255; }

extern "C" void kernel_launch(void* const* d_in, const int* in_sizes, int n_in,
                              void* d_out, int out_size, void* d_ws, size_t ws_size,
                              hipStream_t stream) {
    const void* x     = d_in[0];
    const void* eidx  = d_in[1];
    const void* W1    = d_in[2];
    const void* b1    = d_in[3];
    const void* convW = d_in[4];
    const void* W2    = d_in[5];
    const void* b2    = d_in[6];

    char* p = (char*)d_ws;
    size_t off = 0;
    auto alloc = [&](size_t bytes) { void* r = p + off; off += align256(bytes); return r; };
    int*            flags   = (int*)alloc(256);
    int*            cnt     = (int*)alloc((size_t)NKEY * 4);        // 5.2 MB
    int*            fill    = (int*)alloc((size_t)NKEY * 4);        // 5.2 MB
    int*            keyptr  = (int*)alloc((size_t)(NKEY + 1) * 4);  // 5.2 MB
    int*            bsum    = (int*)alloc((size_t)KB * 4);
    float*          dinv    = (float*)alloc((size_t)NN * 4);
    int*            col     = (int*)alloc((size_t)NE * 4);          // 12.8 MB
    float*          x0      = (float*)alloc((size_t)NN * HD * 4);   // 25.6 MB
    unsigned short* hA      = (unsigned short*)alloc((size_t)NN * HD * 2);
    unsigned short* hB      = (unsigned short*)alloc((size_t)NN * HD * 2);

    detect_kernel<<<1, 64, 0, stream>>>(x, eidx, flags);

    hipMemsetAsync(cnt, 0, (size_t)NKEY * 4, stream);
    hipMemsetAsync(fill, 0, (size_t)NKEY * 4, stream);
    key_count<<<(NE + 255) / 256, 256, 0, stream>>>(eidx, flags, cnt);
    scan_reduce<<<KB, 1024, 0, stream>>>(cnt, bsum);
    scan_mid<<<1, 1024, 0, stream>>>(bsum, keyptr + NKEY);
    scan_final<<<KB, 1024, 0, stream>>>(cnt, bsum, keyptr);
    dinv_kernel<<<(NN + 255) / 256, 256, 0, stream>>>(keyptr, dinv);
    scatter_kernel<<<(NE + 255) / 256, 256, 0, stream>>>(eidx, flags, keyptr, fill, col);

    int fb = (NN + RPB - 1) / RPB;  // 6250 blocks
    x0_kernel<<<fb, 256, 0, stream>>>(x, W1, b1, flags, dinv, x0, hA);

    unsigned short* gin = hA;
    unsigned short* gout = hB;
    for (int l = 0; l < NL; l++) {
        float beta = logf(0.5f / (float)(l + 1) + 1.0f);
        layer_fused<<<fb, 256, 0, stream>>>(keyptr, col, dinv, gin, x0, gout,
                                            convW, l, flags, beta);
        unsigned short* t = gin; gin = gout; gout = t;
    }
    out_kernel<<<(NN + 3) / 4, 256, 0, stream>>>(gin, dinv, W2, b2, flags, (void*)d_out);
}